// Round 19
// baseline (339.099 us; speedup 1.0000x reference)
//
#include <hip/hip_runtime.h>
#include <hip/hip_bf16.h>

#define SEQ   110
#define HALFS 55
#define EMB   102
#define HEAD  192

typedef short bf16x8 __attribute__((ext_vector_type(8)));
typedef float f32x4  __attribute__((ext_vector_type(4)));

#define XS    104               // tile row stride (shorts), 13 granules (odd)
#define XTILE (64 * XS)         // 6656 shorts per tile
#define MTS   128               // Mt row stride (shorts)
#define MTROWS 112
#define MT_SHORTS (MTROWS * MTS)   // 14336
#define WES   128               // WvT e-stride

__device__ __forceinline__ short f2bf(float f) {
    unsigned u = __float_as_uint(f);
    unsigned r = u + 0x7fffu + ((u >> 16) & 1u);   // RNE
    return (short)(r >> 16);
}
__device__ __forceinline__ unsigned pk2(float a, float b) {
    return ((unsigned)(unsigned short)f2bf(b) << 16) | (unsigned short)f2bf(a);
}

// ws layout: [ Mt : 112x128 bf16 ][ WvT : 192x128 bf16 ]
// Mt[i][j] = scale * sum_h Wq[j][h] * Wk[i][h]; WvT[h][e] = Wv[e][h]; zero-padded.
__global__ void prep(const float* __restrict__ Wq, const float* __restrict__ Wk,
                     const float* __restrict__ Wv, short* __restrict__ ws) {
    int flat = blockIdx.x * 256 + threadIdx.x;
    if (flat < MT_SHORTS) {
        int i = flat >> 7, j = flat & 127;
        float v = 0.0f;
        if (i < EMB && j < EMB) {
            const float4* q4 = (const float4*)(Wq + j * HEAD);
            const float4* k4 = (const float4*)(Wk + i * HEAD);
            float s = 0.0f;
            #pragma unroll 4
            for (int h4 = 0; h4 < HEAD / 4; ++h4) {
                float4 a = q4[h4], b = k4[h4];
                s += a.x * b.x + a.y * b.y + a.z * b.z + a.w * b.w;
            }
            v = s * 0.07216878364870322f;   // 1/sqrt(192)
        }
        ws[flat] = f2bf(v);
    } else if (flat < MT_SHORTS + HEAD * WES) {
        int idx = flat - MT_SHORTS;
        int h = idx >> 7, e = idx & 127;
        float v = (e < EMB) ? Wv[e * HEAD + h] : 0.0f;
        ws[flat] = f2bf(v);
    }
}

// ---- staging (R13-proven form), parameterized by tile base + reg arrays ----
#define LOADX(batch, v0, v1) do { \
    const float4* xb4_ = (const float4*)(x + (size_t)(batch) * (SEQ * EMB)); \
    _Pragma("unroll") \
    for (int it_ = 0; it_ < 6; ++it_) { \
        int i4_ = tid + it_ * 512; \
        if (i4_ < 2805) { float4 v_ = xb4_[i4_]; v0[it_] = pk2(v_.x, v_.y); v1[it_] = pk2(v_.z, v_.w); } \
    } \
} while (0)

#define STAGEX(base, v0, v1) do { \
    _Pragma("unroll") \
    for (int it_ = 0; it_ < 6; ++it_) { \
        int i4_ = tid + it_ * 512; \
        if (i4_ < 2805) { \
            int fc_  = i4_ * 4; \
            int row_ = (int)(((unsigned long long)fc_ * 41121ull) >> 22); \
            int e_   = fc_ - row_ * EMB; \
            int tile_ = row_ >= HALFS; \
            int lr_   = row_ - HALFS * tile_; \
            int ba_   = (base) + tile_ * XTILE + lr_ * XS + e_; \
            if (e_ == 100) { \
                int rowb_  = row_ + 1; \
                int tileb_ = rowb_ >= HALFS; \
                int lrb_   = rowb_ - HALFS * tileb_; \
                *(unsigned*)(u + ba_) = v0[it_]; \
                *(unsigned*)(u + (base) + tileb_ * XTILE + lrb_ * XS) = v1[it_]; \
            } else { \
                uint2 t2_; t2_.x = v0[it_]; t2_.y = v1[it_]; \
                *(uint2*)(u + ba_) = t2_; \
            } \
        } \
    } \
} while (0)

// ---- y = x_h @ G -> yh_ (R13-proven) ----
#define YGEMM(xh_, yh_) do { \
    _Pragma("unroll") \
    for (int stl = 0; stl < 4; ++stl) { \
        const short* xb_ = (xh_) + (16 * stl + r) * XS; \
        bf16x8 bx_[4]; \
        _Pragma("unroll") \
        for (int kk = 0; kk < 3; ++kk) bx_[kk] = *(const bf16x8*)(xb_ + 32 * kk + 8 * g); \
        bx_[3] = zz; \
        if (g == 0) bx_[3] = *(const bf16x8*)(xb_ + 96); \
        _Pragma("unroll") \
        for (int mi2 = 0; mi2 < 2; ++mi2) { \
            const int mt = w4 + 4 * mi2; \
            if (mt < 7) { \
                f32x4 acc = {0.f, 0.f, 0.f, 0.f}; \
                _Pragma("unroll") \
                for (int kk = 0; kk < 4; ++kk) \
                    acc = __builtin_amdgcn_mfma_f32_16x16x32_bf16(am[mi2][kk], bx_[kk], acc, 0, 0, 0); \
                if (mt < 6 || g < 2) { \
                    uint2 t2_; t2_.x = pk2(acc[0], acc[1]); t2_.y = pk2(acc[2], acc[3]); \
                    *(uint2*)((yh_) + (16 * stl + r) * XS + 16 * mt + 4 * g) = t2_; \
                } \
            } \
        } \
    } \
} while (0)

// ---- v-GEMM (streamed ax, R18-proven) + v-exchange -> va_ ----
#define VGEMM(xo_, va_) do { \
    unsigned vpk_[4][3][2]; \
    _Pragma("unroll") \
    for (int st = 0; st < 4; ++st) { \
        const short* xb_ = (xo_) + (16 * st + r) * XS; \
        bf16x8 axm_[4]; \
        _Pragma("unroll") \
        for (int kk = 0; kk < 3; ++kk) axm_[kk] = *(const bf16x8*)(xb_ + 32 * kk + 8 * g); \
        axm_[3] = zz; \
        if (g == 0) axm_[3] = *(const bf16x8*)(xb_ + 96); \
        _Pragma("unroll") \
        for (int mi = 0; mi < 3; ++mi) { \
            f32x4 acc = {0.f, 0.f, 0.f, 0.f}; \
            _Pragma("unroll") \
            for (int kk = 0; kk < 4; ++kk) \
                acc = __builtin_amdgcn_mfma_f32_16x16x32_bf16(axm_[kk], wvf[mi][kk], acc, 0, 0, 0); \
            vpk_[st][mi][0] = pk2(acc[0], acc[1]); \
            vpk_[st][mi][1] = pk2(acc[2], acc[3]); \
        } \
    } \
    _Pragma("unroll") \
    for (int mi = 0; mi < 3; ++mi) { \
        unsigned e00 = (unsigned)__shfl((int)vpk_[0][mi][0], src0), e01 = (unsigned)__shfl((int)vpk_[0][mi][1], src0); \
        unsigned e02 = (unsigned)__shfl((int)vpk_[0][mi][0], src1), e03 = (unsigned)__shfl((int)vpk_[0][mi][1], src1); \
        unsigned f00 = (unsigned)__shfl((int)vpk_[1][mi][0], src0), f01 = (unsigned)__shfl((int)vpk_[1][mi][1], src0); \
        unsigned f02 = (unsigned)__shfl((int)vpk_[1][mi][0], src1), f03 = (unsigned)__shfl((int)vpk_[1][mi][1], src1); \
        uint4 u0_; \
        u0_.x = hi ? f00 : e00; u0_.y = hi ? f01 : e01; u0_.z = hi ? f02 : e02; u0_.w = hi ? f03 : e03; \
        unsigned e10 = (unsigned)__shfl((int)vpk_[2][mi][0], src0), e11 = (unsigned)__shfl((int)vpk_[2][mi][1], src0); \
        unsigned e12 = (unsigned)__shfl((int)vpk_[2][mi][0], src1), e13 = (unsigned)__shfl((int)vpk_[2][mi][1], src1); \
        unsigned f10 = (unsigned)__shfl((int)vpk_[3][mi][0], src0), f11 = (unsigned)__shfl((int)vpk_[3][mi][1], src0); \
        unsigned f12 = (unsigned)__shfl((int)vpk_[3][mi][0], src1), f13 = (unsigned)__shfl((int)vpk_[3][mi][1], src1); \
        uint4 u1_; \
        u1_.x = hi ? f10 : e10; u1_.y = hi ? f11 : e11; u1_.z = hi ? f12 : e12; u1_.w = hi ? f13 : e13; \
        __builtin_memcpy(&va_[mi][0], &u0_, 16); \
        __builtin_memcpy(&va_[mi][1], &u1_, 16); \
    } \
} while (0)

// ---- scores + softmax + P write overlaying yh_ (R16-proven overlay, R18 streamed ax) ----
#define SCORES_P(xo_, yh_) do { \
    bf16x8 by_[4]; \
    { \
        const short* yb_ = (yh_) + (16 * w4 + r) * XS; \
        _Pragma("unroll") \
        for (int kk = 0; kk < 3; ++kk) by_[kk] = *(const bf16x8*)(yb_ + 32 * kk + 8 * g); \
        by_[3] = zz; \
        if (g == 0) by_[3] = *(const bf16x8*)(yb_ + 96); \
    } \
    float sc_[4][4]; \
    _Pragma("unroll") \
    for (int mt = 0; mt < 4; ++mt) { \
        const short* xb_ = (xo_) + (16 * mt + r) * XS; \
        bf16x8 axm_[4]; \
        _Pragma("unroll") \
        for (int kk = 0; kk < 3; ++kk) axm_[kk] = *(const bf16x8*)(xb_ + 32 * kk + 8 * g); \
        axm_[3] = zz; \
        if (g == 0) axm_[3] = *(const bf16x8*)(xb_ + 96); \
        f32x4 acc = {0.f, 0.f, 0.f, 0.f}; \
        _Pragma("unroll") \
        for (int kk = 0; kk < 4; ++kk) \
            acc = __builtin_amdgcn_mfma_f32_16x16x32_bf16(axm_[kk], by_[kk], acc, 0, 0, 0); \
        _Pragma("unroll") \
        for (int j = 0; j < 4; ++j) sc_[mt][j] = acc[j]; \
    } \
    _Pragma("unroll") \
    for (int j = 0; j < 4; ++j) \
        if (48 + 4 * g + j >= HALFS) sc_[3][j] = -1e30f; \
    float mx_ = -1e30f; \
    _Pragma("unroll") \
    for (int mt = 0; mt < 4; ++mt) { \
        _Pragma("unroll") \
        for (int j = 0; j < 4; ++j) mx_ = fmaxf(mx_, sc_[mt][j]); \
    } \
    mx_ = fmaxf(mx_, __shfl_xor(mx_, 16)); \
    mx_ = fmaxf(mx_, __shfl_xor(mx_, 32)); \
    float pr_[4][4]; \
    float sum_ = 0.f; \
    _Pragma("unroll") \
    for (int mt = 0; mt < 4; ++mt) { \
        _Pragma("unroll") \
        for (int j = 0; j < 4; ++j) { pr_[mt][j] = __expf(sc_[mt][j] - mx_); sum_ += pr_[mt][j]; } \
    } \
    sum_ += __shfl_xor(sum_, 16); \
    sum_ += __shfl_xor(sum_, 32); \
    float rs_ = 1.0f / sum_; \
    _Pragma("unroll") \
    for (int mt = 0; mt < 4; ++mt) { \
        uint2 t2_; \
        t2_.x = pk2(pr_[mt][0] * rs_, pr_[mt][1] * rs_); \
        t2_.y = pk2(pr_[mt][2] * rs_, pr_[mt][3] * rs_); \
        *(uint2*)((yh_) + (16 * w4 + r) * XS + 16 * mt + 4 * g) = t2_; \
    } \
} while (0)

// ---- PV + stores (R16-proven overlay reads) ----
#define PVOUT(yh_, va_, pbatch) do { \
    const size_t obase_ = (size_t)(pbatch) * (SEQ * HEAD) + (size_t)(h * HALFS) * HEAD; \
    _Pragma("unroll") \
    for (int c = 0; c < 4; ++c) { \
        const short* pb_ = (yh_) + (16 * c + r) * XS + 8 * g; \
        bf16x8 bp0_ = *(const bf16x8*)(pb_); \
        bf16x8 bp1_ = *(const bf16x8*)(pb_ + 32); \
        const int srow_ = 16 * c + r; \
        const bool valid_ = srow_ < HALFS; \
        float* orow_ = out + obase_ + (size_t)srow_ * HEAD; \
        _Pragma("unroll") \
        for (int mi = 0; mi < 3; ++mi) { \
            f32x4 acc = {0.f, 0.f, 0.f, 0.f}; \
            acc = __builtin_amdgcn_mfma_f32_16x16x32_bf16(va_[mi][0], bp0_, acc, 0, 0, 0); \
            acc = __builtin_amdgcn_mfma_f32_16x16x32_bf16(va_[mi][1], bp1_, acc, 0, 0, 0); \
            if (valid_) { \
                float4 st4_; st4_.x = acc[0]; st4_.y = acc[1]; st4_.z = acc[2]; st4_.w = acc[3]; \
                *(float4*)(orow_ + 16 * (w4 + 4 * mi) + 4 * g) = st4_; \
            } \
        } \
    } \
} while (0)

// 512 blocks x 512 threads; each iteration processes TWO independent batches
// (pA = p, pB = p+gridDim; stride 2*gridDim) so every barrier-to-barrier region
// holds two independent dep-chains (2x ILP), 1.5 barriers/batch. LDS = 8 x-tiles
// = 104KB (P overlays y, R16-proven). Phase code = union of passing R13/R16/R18.
__global__ __launch_bounds__(512, 2)
void attn_head(const float* __restrict__ x, const short* __restrict__ ws,
               float* __restrict__ out, int B) {
    const int tid  = threadIdx.x;
    const int w8   = tid >> 6;        // 0..7
    const int h    = w8 >> 2;         // half group
    const int w4   = w8 & 3;          // wave within group
    const int lane = tid & 63;
    const int g    = lane >> 4;
    const int r    = lane & 15;

    __shared__ __attribute__((aligned(16))) short u[8 * XTILE];   // 106496 B

    short* xhA = u + h * XTILE;
    short* xoA = u + (h ^ 1) * XTILE;
    short* xhB = u + (2 + h) * XTILE;
    short* xoB = u + (2 + (h ^ 1)) * XTILE;
    short* yhA = u + (4 + h) * XTILE;     // P_A overlays after reads
    short* yhB = u + (6 + h) * XTILE;     // P_B overlays after reads

    const short* Mt  = ws;
    const short* WvT = ws + MT_SHORTS;

    bf16x8 wvf[3][4];
    #pragma unroll
    for (int mi = 0; mi < 3; ++mi) {
        const int hrow = 16 * (w4 + 4 * mi) + r;
        #pragma unroll
        for (int kk = 0; kk < 4; ++kk)
            wvf[mi][kk] = *(const bf16x8*)(WvT + hrow * WES + 32 * kk + 8 * g);
    }

    // one-time pad zeroing of all 4 x tiles (rows 55..63; cols 102/103 rows 0..54)
    {
        unsigned long long* z = (unsigned long long*)u;
        #pragma unroll
        for (int i0 = 0; i0 < 2; ++i0) {
            int ii = tid + i0 * 512;
            if (ii < 936) {                      // 4 tiles x 234 u64 pad rows
                int tt = ii / 234;
                int o  = ii - tt * 234;
                z[tt * 1664 + 1430 + o] = 0ull;  // tile tt pad rows 55..63
            }
        }
        if (tid < 220) {                         // 4 tiles x 55 rows, cols 102/103
            int tt  = tid / 55;
            int row = tid - tt * 55;
            *(unsigned*)(u + tt * XTILE + row * XS + 102) = 0u;
        }
    }

    const int gsz    = (int)gridDim.x;
    const int stride2 = 2 * gsz;
    unsigned xvA0[6], xvA1[6], xvB0[6], xvB1[6];

    LOADX((int)blockIdx.x, xvA0, xvA1);
    STAGEX(0, xvA0, xvA1);
    if ((int)blockIdx.x + gsz < B) {
        LOADX((int)blockIdx.x + gsz, xvB0, xvB1);
        STAGEX(2 * XTILE, xvB0, xvB1);
    }

    bf16x8 zz = {};
    const int src0 = ((g & 1) << 5) + r;
    const int src1 = src0 + 16;
    const bool hi  = (g >> 1) != 0;

    #pragma unroll 1
    for (int p = blockIdx.x; p < B; p += stride2) {
        const int pB   = p + gsz;
        const bool hasB = pB < B;
        const int pnA  = p + stride2;
        const int pnB  = pB + stride2;

        __syncthreads();                 // bar1: xA,xB staged & visible

        if (pnA < B) LOADX(pnA, xvA0, xvA1);

        bf16x8 am[2][4];
        #pragma unroll
        for (int mi2 = 0; mi2 < 2; ++mi2) {
            const int mt = w4 + 4 * mi2;
            #pragma unroll
            for (int kk = 0; kk < 4; ++kk)
                am[mi2][kk] = (mt < 7) ? *(const bf16x8*)(Mt + (16 * mt + r) * MTS + 32 * kk + 8 * g) : zz;
        }

        YGEMM(xhA, yhA);
        if (hasB) YGEMM(xhB, yhB);

        bf16x8 vaA[3][2], vaB[3][2];
        VGEMM(xoA, vaA);
        if (hasB) VGEMM(xoB, vaB);

        __syncthreads();                 // bar2: yA,yB visible

        SCORES_P(xoA, yhA);
        if (hasB) SCORES_P(xoB, yhB);

        if (hasB && pnB < B) LOADX(pnB, xvB0, xvB1);

        __syncthreads();                 // P-bar: P overlays visible; all x reads done

        if (pnA < B) STAGEX(0, xvA0, xvA1);
        if (pnB < B) STAGEX(2 * XTILE, xvB0, xvB1);

        PVOUT(yhA, vaA, p);
        if (hasB) PVOUT(yhB, vaB, pB);
    }
}

extern "C" void kernel_launch(void* const* d_in, const int* in_sizes, int n_in,
                              void* d_out, int out_size, void* d_ws, size_t ws_size,
                              hipStream_t stream) {
    const float* x  = (const float*)d_in[0];
    const float* Wq = (const float*)d_in[1];
    const float* Wk = (const float*)d_in[2];
    const float* Wv = (const float*)d_in[3];
    short* ws = (short*)d_ws;                       // needs (14336+24576)*2 = 77824 B
    int B = in_sizes[0] / (SEQ * EMB);              // 8192
    int prep_elems = MT_SHORTS + HEAD * WES;
    prep<<<(prep_elems + 255) / 256, 256, 0, stream>>>(Wq, Wk, Wv, ws);
    attn_head<<<512, 512, 0, stream>>>(x, ws, (float*)d_out, B);
}